// Round 5
// baseline (126.272 us; speedup 1.0000x reference)
//
#include <hip/hip_runtime.h>

// VQ-VAE VectorQuantizer forward, fp32 in/out, MFMA (x bf16-split) distances.
// inputs:  d_in[0] = x (64,64,32,32) NCHW fp32; d_in[1] = embedding (512,64) fp32
// outputs (concat fp32): [loss(1) | quantized NCHW (4194304) | perplexity(1) | quantized NHWC-flat (4194304)]

constexpr int DIM    = 64;
constexpr int KC     = 512;
constexpr int HW     = 1024;
constexpr int NPTS   = 65536;
constexpr int QELEMS = NPTS * DIM;

typedef float f32x16 __attribute__((ext_vector_type(16)));
typedef short bf16x8 __attribute__((ext_vector_type(8)));

__device__ inline unsigned short f2bf(float f) {          // RNE float->bf16
    unsigned u = __float_as_uint(f);
    u += 0x7FFF + ((u >> 16) & 1);
    return (unsigned short)(u >> 16);
}
__device__ inline float bf2f(unsigned short s) { return __uint_as_float(((unsigned)s) << 16); }

__device__ inline uint4 pack8(const unsigned short* s) {
    return make_uint4((unsigned)s[0] | ((unsigned)s[1] << 16),
                      (unsigned)s[2] | ((unsigned)s[3] << 16),
                      (unsigned)s[4] | ((unsigned)s[5] << 16),
                      (unsigned)s[6] | ((unsigned)s[7] << 16));
}

// ---------------------------------------------------------------------------
// Prep: EH[hb][c] = bf16 A-fragment of -e (hb=2ks+hi: k = 16ks+4hi+(j&3)+8(j>>2)).
// hb=8: [nh,nl,0..] = bf16-split of (0.5 + ||e||^2/2); hb=9: zeros. 16B/frag.
__global__ __launch_bounds__(256)
void vq_prep_kernel(const float* __restrict__ emb, unsigned short* __restrict__ EH)
{
    const int t = blockIdx.x * 256 + threadIdx.x;
    if (t < 4096) {
        const int c = t & 511, hb = t >> 9;
        const int d0 = 16 * (hb >> 1) + 4 * (hb & 1);
        const float* e = emb + (size_t)c * DIM;
        float4 v0 = *reinterpret_cast<const float4*>(e + d0);
        float4 v1 = *reinterpret_cast<const float4*>(e + d0 + 8);
        unsigned short s[8];
        s[0]=f2bf(-v0.x); s[1]=f2bf(-v0.y); s[2]=f2bf(-v0.z); s[3]=f2bf(-v0.w);
        s[4]=f2bf(-v1.x); s[5]=f2bf(-v1.y); s[6]=f2bf(-v1.z); s[7]=f2bf(-v1.w);
        *reinterpret_cast<uint4*>(EH + (size_t)(hb * KC + c) * 8) = pack8(s);
    } else if (t < 4608) {
        const int c = t - 4096;
        const float4* er = reinterpret_cast<const float4*>(emb + (size_t)c * DIM);
        float nrm = 0.f;
        #pragma unroll
        for (int i = 0; i < DIM / 4; ++i) {
            float4 v = er[i];
            nrm = fmaf(v.x,v.x,fmaf(v.y,v.y,fmaf(v.z,v.z,fmaf(v.w,v.w,nrm))));
        }
        float val = 0.5f + 0.5f * nrm;           // positive-shifted norm term
        unsigned short nh = f2bf(val);
        unsigned short nl = f2bf(val - bf2f(nh));
        unsigned short ext[8] = {nh, nl, 0,0,0,0,0,0};
        unsigned short zer[8] = {0,0,0,0,0,0,0,0};
        *reinterpret_cast<uint4*>(EH + (size_t)(8 * KC + c) * 8) = pack8(ext);
        *reinterpret_cast<uint4*>(EH + (size_t)(9 * KC + c) * 8) = pack8(zer);
    }
}

// ---------------------------------------------------------------------------
// Main: wave = 32 points x 256 codes (4 chunks of 64). Pairs of waves (same 32
// points, disjoint 256-code halves) combine via 512B LDS. No other LDS/barrier.
// acc = 0.5 + ||e||^2/2 - x.e  (>0) -> float bits are order-preserving; code
// index packed into the 9 low mantissa bits -> argmin == u32-min, exact
// lowest-index tie-break.
__global__ __launch_bounds__(256, 4)
void vq_main_kernel(const float* __restrict__ x, const float* __restrict__ emb,
                    const unsigned short* __restrict__ EH,
                    int* __restrict__ hist, float* __restrict__ loss_accum,
                    float* __restrict__ out_nchw, float* __restrict__ out_flat)
{
    __shared__ unsigned wkeys[4][32];

    const int tid  = threadIdx.x;
    const int w    = tid >> 6, lane = tid & 63;
    const int lo   = lane & 31, hi = lane >> 5;
    const int pair = w >> 1,  pw  = w & 1;

    const int n0  = blockIdx.x * 64 + pair * 32;   // this pair's 32 points
    const int b   = n0 >> 10;
    const int hw0 = n0 & (HW - 1);

    // ---- build B fragments (point = lo) from global x; bf16 hi/lo split
    bf16x8 BH[4], BL[4];
    float xnorm = 0.f;
    const float* xp = x + (size_t)b * (DIM * HW) + hw0 + lo;
    #pragma unroll
    for (int ks = 0; ks < 4; ++ks) {
        bf16x8 bh, bl;
        #pragma unroll
        for (int j = 0; j < 8; ++j) {
            const int d = 16 * ks + 4 * hi + (j & 3) + 8 * (j >> 2);
            float v = xp[(size_t)d * HW];
            xnorm = fmaf(v, v, xnorm);
            unsigned short h = f2bf(v);
            bh[j] = (short)h;
            bl[j] = (short)f2bf(v - bf2f(h));
        }
        BH[ks] = bh; BL[ks] = bl;
    }
    bf16x8 B1 = {(short)0x3F80, (short)0x3F80, 0,0,0,0,0,0};   // 1.0 at k=0,1

    // ---- 4 chunks x 64 codes: MFMA + packed-key argmin
    unsigned rkey = 0xFFFFFFFFu;
    const int cbase = pw * 256;
    #pragma unroll
    for (int cc = 0; cc < 4; ++cc) {
        const int c0 = cbase + 64 * cc;
        f32x16 a0 = {}, a1 = {};
        #pragma unroll
        for (int ks = 0; ks < 4; ++ks) {
            const int hb = 2 * ks + hi;
            bf16x8 A0 = *reinterpret_cast<const bf16x8*>(EH + (size_t)(hb * KC + c0 + lo) * 8);
            bf16x8 A1 = *reinterpret_cast<const bf16x8*>(EH + (size_t)(hb * KC + c0 + 32 + lo) * 8);
            a0 = __builtin_amdgcn_mfma_f32_32x32x16_bf16(A0, BH[ks], a0, 0, 0, 0);
            a1 = __builtin_amdgcn_mfma_f32_32x32x16_bf16(A1, BH[ks], a1, 0, 0, 0);
            a0 = __builtin_amdgcn_mfma_f32_32x32x16_bf16(A0, BL[ks], a0, 0, 0, 0);
            a1 = __builtin_amdgcn_mfma_f32_32x32x16_bf16(A1, BL[ks], a1, 0, 0, 0);
        }
        {   // fold 0.5 + norm/2 (hi=0 half supplies it; hi=1 reads zero block)
            const int hb = 8 + hi;
            bf16x8 N0 = *reinterpret_cast<const bf16x8*>(EH + (size_t)(hb * KC + c0 + lo) * 8);
            bf16x8 N1 = *reinterpret_cast<const bf16x8*>(EH + (size_t)(hb * KC + c0 + 32 + lo) * 8);
            a0 = __builtin_amdgcn_mfma_f32_32x32x16_bf16(N0, B1, a0, 0, 0, 0);
            a1 = __builtin_amdgcn_mfma_f32_32x32x16_bf16(N1, B1, a1, 0, 0, 0);
        }
        // packed keys: code = c0 + 32*tile + (r&3) + 8*(r>>2) + 4*hi  (bits disjoint)
        const unsigned kb0 = (unsigned)(c0 + 4 * hi), kb1 = kb0 + 32;
        unsigned m0 = 0xFFFFFFFFu, m1 = 0xFFFFFFFFu, m2 = 0xFFFFFFFFu, m3 = 0xFFFFFFFFu;
        #pragma unroll
        for (int r = 0; r < 16; ++r) {
            const unsigned kc = (unsigned)((r & 3) + 8 * (r >> 2));
            unsigned k0 = (__float_as_uint(a0[r]) & 0xFFFFFE00u) | (kb0 + kc);
            unsigned k1 = (__float_as_uint(a1[r]) & 0xFFFFFE00u) | (kb1 + kc);
            unsigned m  = min(k0, k1);
            if ((r & 3) == 0) m0 = min(m0, m);
            else if ((r & 3) == 1) m1 = min(m1, m);
            else if ((r & 3) == 2) m2 = min(m2, m);
            else m3 = min(m3, m);
        }
        rkey = min(rkey, min(min(m0, m1), min(m2, m3)));
    }

    // ---- combine halves, then pair partner
    rkey  = min(rkey, (unsigned)__shfl_xor((int)rkey, 32, 64));
    xnorm += __shfl_xor(xnorm, 32, 64);
    if (hi == 0) wkeys[w][lo] = rkey;
    __syncthreads();
    const unsigned fkey = min(wkeys[2 * pair][lo], wkeys[2 * pair + 1][lo]);

    // ---- loss + hist (one wave per pair)
    if (pw == 0) {
        const int   code = (int)(fkey & 511u);
        const float v    = __uint_as_float(fkey & 0xFFFFFE00u);
        float ls = (hi == 0) ? (2.f * v - 1.f + xnorm) : 0.f;   // ||x-e||^2
        if (hi == 0) atomicAdd(&hist[code], 1);
        #pragma unroll
        for (int off = 32; off > 0; off >>= 1) ls += __shfl_down(ls, off, 64);
        if (lane == 0) atomicAdd(loss_accum, ls);
    }

    // ---- outputs: even wave writes NCHW, odd wave writes NHWC-flat
    if (pw == 0) {
        const int p = lane >> 1, q = lane & 1;
        const int code = __shfl((int)fkey, p, 64) & 511;
        const float4* er = reinterpret_cast<const float4*>(emb + (size_t)code * DIM) + q * 8;
        float* ob = out_nchw + (size_t)b * (DIM * HW) + hw0 + p;
        #pragma unroll
        for (int j = 0; j < 8; ++j) {
            float4 vv = er[j];
            const int d = q * 32 + 4 * j;
            ob[(size_t)(d + 0) * HW] = vv.x;
            ob[(size_t)(d + 1) * HW] = vv.y;
            ob[(size_t)(d + 2) * HW] = vv.z;
            ob[(size_t)(d + 3) * HW] = vv.w;
        }
    } else {
        #pragma unroll
        for (int i = 0; i < 16; ++i) {
            const int p = 2 * i + hi;
            const int code = __shfl((int)fkey, p, 64) & 511;
            float2 vv = *reinterpret_cast<const float2*>(emb + (size_t)code * DIM + 2 * lo);
            *reinterpret_cast<float2*>(out_flat + (size_t)(n0 + p) * DIM + 2 * lo) = vv;
        }
    }
}

// ---------------------------------------------------------------------------
__global__ __launch_bounds__(512, 1)
void vq_finalize_kernel(const int* __restrict__ hist, const float* __restrict__ loss_accum,
                        float* __restrict__ out_loss, float* __restrict__ out_perp)
{
    __shared__ float wsum[8];
    const int tid = threadIdx.x;
    const float p = (float)hist[tid] * (1.0f / (float)NPTS);
    float t = p * logf(p + 1e-10f);
    #pragma unroll
    for (int off = 32; off > 0; off >>= 1)
        t += __shfl_down(t, off, 64);
    if ((tid & 63) == 0) wsum[tid >> 6] = t;
    __syncthreads();
    if (tid == 0) {
        float s = 0.f;
        #pragma unroll
        for (int w = 0; w < 8; ++w) s += wsum[w];
        *out_perp = expf(-s);
        *out_loss = (*loss_accum) * 1.25f / (float)QELEMS;   // q_latent + 0.25*e_latent (equal in fwd)
    }
}

extern "C" void kernel_launch(void* const* d_in, const int* in_sizes, int n_in,
                              void* d_out, int out_size, void* d_ws, size_t ws_size,
                              hipStream_t stream)
{
    const float* x   = (const float*)d_in[0];
    const float* emb = (const float*)d_in[1];
    float* out = (float*)d_out;

    float*          loss_accum = (float*)d_ws;
    int*            hist       = (int*)((char*)d_ws + 64);
    unsigned short* EH         = (unsigned short*)((char*)d_ws + 4096);   // 10*512*16 = 81920 B

    hipMemsetAsync(d_ws, 0, 4096, stream);   // loss accum + histogram

    vq_prep_kernel<<<18, 256, 0, stream>>>(emb, EH);

    vq_main_kernel<<<NPTS / 64, 256, 0, stream>>>(x, emb, EH, hist, loss_accum,
                                                  out + 1, out + 2 + QELEMS);

    vq_finalize_kernel<<<1, 512, 0, stream>>>(hist, loss_accum, out, out + 1 + QELEMS);
}